// Round 4
// baseline (448.171 us; speedup 1.0000x reference)
//
#include <hip/hip_runtime.h>
#include <hip/hip_bf16.h>

typedef __attribute__((ext_vector_type(4))) float f32x4;
typedef __attribute__((ext_vector_type(8))) short s16x8;
typedef unsigned short u16;
typedef unsigned int u32;

// ---------- helpers ----------
__device__ inline u16 f2bf(float f) {
    union { float f; u32 u; } v; v.f = f;
    u32 r = v.u + 0x7FFFu + ((v.u >> 16) & 1u);   // RNE
    return (u16)(r >> 16);
}
__device__ inline float bfbits2f(u32 hi_bits) {   // pass (bits << 16)
    union { u32 u; float f; } v; v.u = hi_bits; return v.f;
}

// ---------- weight prep ----------
__global__ __launch_bounds__(256) void cvt_f32_bf16(const float* __restrict__ in,
                                                    u16* __restrict__ out, int n) {
    for (int i = blockIdx.x * 256 + threadIdx.x; i < n; i += gridDim.x * 256)
        out[i] = f2bf(in[i]);
}

// w1cat[h][k] (1024 x 384): h<512 -> W1a[k][h], else W1b[k][h-512]
__global__ __launch_bounds__(256) void build_w1cat(const float* __restrict__ W1a,
                                                   const float* __restrict__ W1b,
                                                   u16* __restrict__ out) {
    int idx = blockIdx.x * 256 + threadIdx.x;
    if (idx >= 1024 * 384) return;
    int h = idx / 384, k = idx - h * 384;
    float v = (h < 512) ? W1a[k * 512 + h] : W1b[k * 512 + (h - 512)];
    out[idx] = f2bf(v);
}

// W2h[h][kk] = sum_o W2[h][o] * Whead[o][kk];  bias7[kk] = b2 @ Whead[:,kk] + bhead[kk]
__global__ __launch_bounds__(256) void build_w2h(
    const float* __restrict__ W2, const float* __restrict__ b2,
    const float* __restrict__ Wp, const float* __restrict__ bp,
    const float* __restrict__ Wpv, const float* __restrict__ bpv,
    const float* __restrict__ Wr, const float* __restrict__ br,
    const float* __restrict__ Wrv, const float* __restrict__ brv,
    float* __restrict__ W2h, float* __restrict__ bias7) {
    int idx = blockIdx.x * 256 + threadIdx.x;
    if (idx < 512 * 7) {
        int h = idx / 7, kk = idx - h * 7;
        float s = 0.f;
        for (int o = 0; o < 256; o++) {
            float w = (kk < 2) ? Wp[o * 2 + kk]
                    : (kk < 4) ? Wpv[o * 2 + kk - 2]
                    : (kk < 6) ? Wr[o * 2 + kk - 4]
                               : Wrv[o];
            s += W2[h * 256 + o] * w;
        }
        W2h[idx] = s;
    }
    if (idx < 7) {
        float s = (idx < 2) ? bp[idx] : (idx < 4) ? bpv[idx - 2]
                : (idx < 6) ? br[idx - 4] : brv[0];
        for (int o = 0; o < 256; o++) {
            float w = (idx < 2) ? Wp[o * 2 + idx]
                    : (idx < 4) ? Wpv[o * 2 + idx - 2]
                    : (idx < 6) ? Wr[o * 2 + idx - 4]
                                : Wrv[o];
            s += b2[o] * w;
        }
        bias7[idx] = s;
    }
}

// ---------- im2col + cvt: img (256,3,224,224) f32 -> patches (12544 x 3072) bf16 ----------
__global__ __launch_bounds__(256) void im2col_kernel(const float* __restrict__ img,
                                                     u16* __restrict__ patches) {
    const int NCHUNK = 12544 * 384;            // chunks of 8 bf16
    for (int cid = blockIdx.x * 256 + threadIdx.x; cid < NCHUNK; cid += gridDim.x * 256) {
        int m = cid / 384;
        int kc = cid - m * 384;
        int k = kc * 8;
        int c = k >> 10;
        int rem = k & 1023;
        int r = rem >> 5;
        int cc = rem & 31;                     // multiple of 8 -> stays inside one 32-col row
        int n = m / 49;
        int s = m - n * 49;
        int py = s / 7;
        int px = s - py * 7;
        const float* src = img + (((size_t)(n * 3 + c) * 224 + py * 32 + r) * 224 + px * 32 + cc);
        float4 v0 = *(const float4*)src;
        float4 v1 = *(const float4*)(src + 4);
        s16x8 o;
        o[0] = (short)f2bf(v0.x); o[1] = (short)f2bf(v0.y);
        o[2] = (short)f2bf(v0.z); o[3] = (short)f2bf(v0.w);
        o[4] = (short)f2bf(v1.x); o[5] = (short)f2bf(v1.y);
        o[6] = (short)f2bf(v1.z); o[7] = (short)f2bf(v1.w);
        *(s16x8*)(patches + (size_t)cid * 8) = o;
    }
}

// ---------- MFMA GEMM: C[M,N] = A[M,K] @ Bt[N,K]^T (+bias[col]), bf16 in/out ----------
// 128x128 tile, BK=64, 4 waves (2x2), 16x16x32 MFMA, global_load_lds width 16.
__global__ __launch_bounds__(256) void gemm_bt(const u16* __restrict__ A,
                                               const u16* __restrict__ Bt,
                                               u16* __restrict__ Cb,
                                               const float* __restrict__ bias,
                                               int M, int N, int K) {
    __shared__ __align__(16) u16 As[128 * 64];
    __shared__ __align__(16) u16 Bs[128 * 64];
    const int tid = threadIdx.x;
    const int wave = tid >> 6, lane = tid & 63;
    const int wr = wave >> 1, wc = wave & 1;
    const int row0 = blockIdx.x * 128, col0 = blockIdx.y * 128;
    const int lr = lane >> 3;               // 0..7
    const int lcb = (lane & 7) * 8;         // element col within 64-wide K slice
    f32x4 acc[4][4] = {};

    for (int k0 = 0; k0 < K; k0 += 64) {
        __syncthreads();                    // protect LDS from prior-iter readers
#pragma unroll
        for (int q = 0; q < 4; q++) {
            int ch = q * 4 + wave;          // 0..15; wave writes contiguous 1KB chunk
            int rA = ch * 8 + lr;
            const u16* gA = A + (size_t)(row0 + rA) * K + k0 + lcb;
            const u16* gB = Bt + (size_t)(col0 + rA) * K + k0 + lcb;
            __builtin_amdgcn_global_load_lds(
                (const __attribute__((address_space(1))) unsigned int*)gA,
                (__attribute__((address_space(3))) unsigned int*)(As + ch * 512), 16, 0, 0);
            __builtin_amdgcn_global_load_lds(
                (const __attribute__((address_space(1))) unsigned int*)gB,
                (__attribute__((address_space(3))) unsigned int*)(Bs + ch * 512), 16, 0, 0);
        }
        __syncthreads();                    // compiler drains vmcnt before barrier
#pragma unroll
        for (int kk = 0; kk < 64; kk += 32) {
            s16x8 af[4], bfr[4];
#pragma unroll
            for (int m = 0; m < 4; m++)
                af[m] = *(const s16x8*)(As + (wr * 64 + m * 16 + (lane & 15)) * 64 + kk + (lane >> 4) * 8);
#pragma unroll
            for (int n = 0; n < 4; n++)
                bfr[n] = *(const s16x8*)(Bs + (wc * 64 + n * 16 + (lane & 15)) * 64 + kk + (lane >> 4) * 8);
#pragma unroll
            for (int m = 0; m < 4; m++)
#pragma unroll
                for (int n = 0; n < 4; n++)
                    acc[m][n] = __builtin_amdgcn_mfma_f32_16x16x32_bf16(af[m], bfr[n], acc[m][n], 0, 0, 0);
        }
    }
    // epilogue: D row=(lane>>4)*4+i, col=lane&15 (m89-verified layout)
#pragma unroll
    for (int m = 0; m < 4; m++) {
        int drow = row0 + wr * 64 + m * 16 + (lane >> 4) * 4;
#pragma unroll
        for (int n = 0; n < 4; n++) {
            int dcol = col0 + wc * 64 + n * 16 + (lane & 15);
            float bv = bias ? bias[dcol] : 0.0f;
#pragma unroll
            for (int i = 0; i < 4; i++)
                Cb[(size_t)(drow + i) * N + dcol] = f2bf(acc[m][n][i] + bv);
        }
    }
}

// ---------- per-edge head computation ----------
// ag: (12544 x 1024) bf16, cols 0..511 = a, 512..1023 = g
__global__ __launch_bounds__(256) void edge_kernel(
    const u16* __restrict__ ag, const float* __restrict__ pos,
    const float* __restrict__ b1, const float* __restrict__ W2h,
    const float* __restrict__ bias7,
    float* __restrict__ edge_out, float* __restrict__ mask_out) {
    __shared__ float red[4][7];
    const int e = blockIdx.x;                // 0..2047
    const int b = e >> 6, ij = e & 63, i = ij >> 3, j = ij & 7;
    const int t = threadIdx.x;
    const float dx = pos[(b * 8 + i) * 3 + 0] - pos[(b * 8 + j) * 3 + 0];
    const float dy = pos[(b * 8 + i) * 3 + 1] - pos[(b * 8 + j) * 3 + 1];
    const bool msk = (dx * dx + dy * dy < 0.25f) && (i != j);
    if (t == 0) mask_out[e] = msk ? 1.0f : 0.0f;
    if (!msk) {                              // block-uniform branch
        if (t < 7) edge_out[e * 7 + t] = 0.0f;
        return;
    }
    const int h0 = t * 2;
    const u16* arow = ag + (size_t)(b * 8 + i) * 49 * 1024 + h0;
    const u16* grow = ag + (size_t)(b * 8 + j) * 49 * 1024 + 512 + h0;
    const float b10 = b1[h0], b11 = b1[h0 + 1];
    float r0 = 0.f, r1 = 0.f;
#pragma unroll 7
    for (int s = 0; s < 49; s++) {
        u32 av = *(const u32*)(arow + (size_t)s * 1024);
        u32 gv = *(const u32*)(grow + (size_t)s * 1024);
        float a0 = bfbits2f(av << 16), a1 = bfbits2f(av & 0xFFFF0000u);
        float g0 = bfbits2f(gv << 16), g1 = bfbits2f(gv & 0xFFFF0000u);
        r0 += fmaxf(a0 + g0 + b10, 0.f);
        r1 += fmaxf(a1 + g1 + b11, 0.f);
    }
    float c[7];
#pragma unroll
    for (int k = 0; k < 7; k++)
        c[k] = r0 * W2h[h0 * 7 + k] + r1 * W2h[(h0 + 1) * 7 + k];
#pragma unroll
    for (int k = 0; k < 7; k++)
#pragma unroll
        for (int off = 32; off; off >>= 1)
            c[k] += __shfl_down(c[k], off, 64);
    const int lane = t & 63, wv = t >> 6;
    if (lane == 0)
        for (int k = 0; k < 7; k++) red[wv][k] = c[k];
    __syncthreads();
    if (t == 0)
        for (int k = 0; k < 7; k++) {
            float v = red[0][k] + red[1][k] + red[2][k] + red[3][k];
            edge_out[e * 7 + k] = v * (1.f / 49.f) + bias7[k];
        }
}

// ---------- launch ----------
extern "C" void kernel_launch(void* const* d_in, const int* in_sizes, int n_in,
                              void* d_out, int out_size, void* d_ws, size_t ws_size,
                              hipStream_t stream) {
    const float* img    = (const float*)d_in[0];
    const float* pos    = (const float*)d_in[1];
    const float* W_patch= (const float*)d_in[3];
    const float* b_patch= (const float*)d_in[4];
    const float* W1a    = (const float*)d_in[5];
    const float* W1b    = (const float*)d_in[6];
    const float* b1     = (const float*)d_in[7];
    const float* W2     = (const float*)d_in[8];
    const float* b2     = (const float*)d_in[9];
    const float* Wp     = (const float*)d_in[10];
    const float* bp     = (const float*)d_in[11];
    const float* Wpv    = (const float*)d_in[12];
    const float* bpv    = (const float*)d_in[13];
    const float* Wr     = (const float*)d_in[14];
    const float* br     = (const float*)d_in[15];
    const float* Wrv    = (const float*)d_in[16];
    const float* brv    = (const float*)d_in[17];

    char* ws = (char*)d_ws;
    u16*   patches = (u16*)(ws + 0);                      // 12544*3072*2 = 77,070,336
    u16*   ag      = (u16*)(ws + 77070336);               // 12544*1024*2 = 25,690,112
    u16*   feats   = (u16*)(ws + 102760448);              // 12544*384*2  =  9,633,792
    u16*   wpb     = (u16*)(ws + 112394240);              // 384*3072*2   =  2,359,296
    u16*   w1cat   = (u16*)(ws + 114753536);              // 1024*384*2   =    786,432
    float* W2h     = (float*)(ws + 115539968);            // 512*7*4      =     14,336
    float* bias7   = (float*)(ws + 115554304);            // 7*4

    float* edge_out   = (float*)d_out;                    // 2048*7
    float* mask_out   = edge_out + 14336;                 // 2048
    float* node_preds = mask_out + 2048;                  // 32*8*3600 = 921,600

    cvt_f32_bf16<<<1024, 256, 0, stream>>>(W_patch, wpb, 384 * 3072);
    build_w1cat<<<1536, 256, 0, stream>>>(W1a, W1b, w1cat);
    build_w2h<<<14, 256, 0, stream>>>(W2, b2, Wp, bp, Wpv, bpv, Wr, br, Wrv, brv, W2h, bias7);
    im2col_kernel<<<4096, 256, 0, stream>>>(img, patches);

    dim3 g1(98, 3);
    gemm_bt<<<g1, 256, 0, stream>>>(patches, wpb, feats, b_patch, 12544, 384, 3072);
    dim3 g2(98, 8);
    gemm_bt<<<g2, 256, 0, stream>>>(feats, w1cat, ag, nullptr, 12544, 1024, 384);

    edge_kernel<<<2048, 256, 0, stream>>>(ag, pos, b1, W2h, bias7, edge_out, mask_out);
    hipMemsetAsync(node_preds, 0, (size_t)921600 * sizeof(float), stream);
}

// Round 6
// 392.111 us; speedup vs baseline: 1.1430x; 1.1430x over previous
//
#include <hip/hip_runtime.h>
#include <hip/hip_bf16.h>

typedef __attribute__((ext_vector_type(4))) float f32x4;
typedef __attribute__((ext_vector_type(8))) short s16x8;
typedef unsigned short u16;
typedef unsigned int u32;

// ---------- helpers ----------
__device__ inline u16 f2bf(float f) {
    union { float f; u32 u; } v; v.f = f;
    u32 r = v.u + 0x7FFFu + ((v.u >> 16) & 1u);   // RNE
    return (u16)(r >> 16);
}
__device__ inline float bfbits2f(u32 hi_bits) {   // pass (bits << 16)
    union { u32 u; float f; } v; v.u = hi_bits; return v.f;
}

// ---------- merged prep: im2col + W_patch cvt + w1cat + w2h, one dispatch ----------
__global__ __launch_bounds__(256) void prep_kernel(
    const float* __restrict__ img, u16* __restrict__ patches,
    const float* __restrict__ W_patch, u16* __restrict__ wpb,
    const float* __restrict__ W1a, const float* __restrict__ W1b,
    u16* __restrict__ w1cat,
    const float* __restrict__ W2, const float* __restrict__ b2,
    const float* __restrict__ Wp, const float* __restrict__ bp,
    const float* __restrict__ Wpv, const float* __restrict__ bpv,
    const float* __restrict__ Wr, const float* __restrict__ br,
    const float* __restrict__ Wrv, const float* __restrict__ brv,
    float* __restrict__ W2h, float* __restrict__ bias7) {
    const int NI = 12544 * 384;          // im2col 8-elem chunks
    const int NW = 147456;               // W_patch 8-elem chunks (384*3072/8)
    const int NC = 1024 * 384;           // w1cat scalars
    const int NH = 3591;                 // 512*7 W2h + 7 bias
    const int total = NI + NW + NC + NH;
    for (int idx = blockIdx.x * 256 + threadIdx.x; idx < total; idx += gridDim.x * 256) {
        if (idx < NI) {
            // im2col: patches[m][k0..k0+8) from img
            int m = idx / 384;
            int kc = idx - m * 384;
            int k = kc * 8;
            int c = k >> 10;
            int rem = k & 1023;
            int r = rem >> 5;
            int cc = rem & 31;
            int n = m / 49;
            int s = m - n * 49;
            int py = s / 7;
            int px = s - py * 7;
            const float* src = img + (((size_t)(n * 3 + c) * 224 + py * 32 + r) * 224 + px * 32 + cc);
            float4 v0 = *(const float4*)src;
            float4 v1 = *(const float4*)(src + 4);
            s16x8 o;
            o[0] = (short)f2bf(v0.x); o[1] = (short)f2bf(v0.y);
            o[2] = (short)f2bf(v0.z); o[3] = (short)f2bf(v0.w);
            o[4] = (short)f2bf(v1.x); o[5] = (short)f2bf(v1.y);
            o[6] = (short)f2bf(v1.z); o[7] = (short)f2bf(v1.w);
            *(s16x8*)(patches + (size_t)idx * 8) = o;
        } else if (idx < NI + NW) {
            int i = (idx - NI) * 8;
            s16x8 o;
#pragma unroll
            for (int q = 0; q < 8; q++) o[q] = (short)f2bf(W_patch[i + q]);
            *(s16x8*)(wpb + i) = o;
        } else if (idx < NI + NW + NC) {
            int t = idx - NI - NW;
            int h = t / 384, k = t - h * 384;
            float v = (h < 512) ? W1a[k * 512 + h] : W1b[k * 512 + (h - 512)];
            w1cat[t] = f2bf(v);
        } else {
            int t = idx - NI - NW - NC;
            if (t < 3584) {
                int h = t / 7, kk = t - h * 7;
                float s = 0.f;
                for (int o = 0; o < 256; o++) {
                    float w = (kk < 2) ? Wp[o * 2 + kk]
                            : (kk < 4) ? Wpv[o * 2 + kk - 2]
                            : (kk < 6) ? Wr[o * 2 + kk - 4]
                                       : Wrv[o];
                    s += W2[h * 256 + o] * w;
                }
                W2h[t] = s;
            } else {
                int kk = t - 3584;
                float s = (kk < 2) ? bp[kk] : (kk < 4) ? bpv[kk - 2]
                        : (kk < 6) ? br[kk - 4] : brv[0];
                for (int o = 0; o < 256; o++) {
                    float w = (kk < 2) ? Wp[o * 2 + kk]
                            : (kk < 4) ? Wpv[o * 2 + kk - 2]
                            : (kk < 6) ? Wr[o * 2 + kk - 4]
                                       : Wrv[o];
                    s += b2[o] * w;
                }
                bias7[kk] = s;
            }
        }
    }
}

// ---------- MFMA GEMM: C[M,N] = A[M,K] @ Bt[N,K]^T (+bias[col]), bf16 in/out ----------
// BM x BN tile, BK=64, 4 waves (2x2), 16x16x32 MFMA, global_load_lds width 16.
template<int BM, int BN>
__global__ __launch_bounds__(256) void gemm_bt(const u16* __restrict__ A,
                                               const u16* __restrict__ Bt,
                                               u16* __restrict__ Cb,
                                               const float* __restrict__ bias,
                                               int M, int N, int K) {
    constexpr int MF = BM / 32;          // M fragments per wave
    constexpr int NF = BN / 32;          // N fragments per wave
    __shared__ __align__(16) u16 As[BM * 64];
    __shared__ __align__(16) u16 Bs[BN * 64];
    const int tid = threadIdx.x;
    const int wave = tid >> 6, lane = tid & 63;
    const int wr = wave >> 1, wc = wave & 1;
    const int row0 = blockIdx.x * BM, col0 = blockIdx.y * BN;
    const int lr = lane >> 3;            // 0..7
    const int lcb = (lane & 7) * 8;      // element col within 64-wide K slice
    f32x4 acc[MF][NF] = {};

    for (int k0 = 0; k0 < K; k0 += 64) {
        __syncthreads();                 // protect LDS from prior-iter readers
#pragma unroll
        for (int q = 0; q < BM / 32; q++) {
            int ch = q * 4 + wave;
            const u16* gA = A + (size_t)(row0 + ch * 8 + lr) * K + k0 + lcb;
            __builtin_amdgcn_global_load_lds(
                (const __attribute__((address_space(1))) unsigned int*)gA,
                (__attribute__((address_space(3))) unsigned int*)(As + ch * 512), 16, 0, 0);
        }
#pragma unroll
        for (int q = 0; q < BN / 32; q++) {
            int ch = q * 4 + wave;
            const u16* gB = Bt + (size_t)(col0 + ch * 8 + lr) * K + k0 + lcb;
            __builtin_amdgcn_global_load_lds(
                (const __attribute__((address_space(1))) unsigned int*)gB,
                (__attribute__((address_space(3))) unsigned int*)(Bs + ch * 512), 16, 0, 0);
        }
        __syncthreads();                 // compiler drains vmcnt before barrier
#pragma unroll
        for (int kk = 0; kk < 64; kk += 32) {
            s16x8 af[MF], bfr[NF];
#pragma unroll
            for (int m = 0; m < MF; m++)
                af[m] = *(const s16x8*)(As + (wr * (BM / 2) + m * 16 + (lane & 15)) * 64 + kk + (lane >> 4) * 8);
#pragma unroll
            for (int n = 0; n < NF; n++)
                bfr[n] = *(const s16x8*)(Bs + (wc * (BN / 2) + n * 16 + (lane & 15)) * 64 + kk + (lane >> 4) * 8);
#pragma unroll
            for (int m = 0; m < MF; m++)
#pragma unroll
                for (int n = 0; n < NF; n++)
                    acc[m][n] = __builtin_amdgcn_mfma_f32_16x16x32_bf16(af[m], bfr[n], acc[m][n], 0, 0, 0);
        }
    }
    // epilogue: D row=(lane>>4)*4+i, col=lane&15 (m89-verified layout)
#pragma unroll
    for (int m = 0; m < MF; m++) {
        int drow = row0 + wr * (BM / 2) + m * 16 + (lane >> 4) * 4;
#pragma unroll
        for (int n = 0; n < NF; n++) {
            int dcol = col0 + wc * (BN / 2) + n * 16 + (lane & 15);
            float bv = bias ? bias[dcol] : 0.0f;
#pragma unroll
            for (int i = 0; i < 4; i++)
                Cb[(size_t)(drow + i) * N + dcol] = f2bf(acc[m][n][i] + bv);
        }
    }
}

// ---------- per-edge head computation (+ node_preds zeroing) ----------
// ag: (12544 x 1024) bf16, cols 0..511 = a, 512..1023 = g
__global__ __launch_bounds__(256) void edge_kernel(
    const u16* __restrict__ ag, const float* __restrict__ pos,
    const float* __restrict__ b1, const float* __restrict__ W2h,
    const float* __restrict__ bias7,
    float* __restrict__ edge_out, float* __restrict__ mask_out,
    float* __restrict__ node_preds) {
    __shared__ float red[4][7];
    const int e = blockIdx.x;                // 0..2047
    const int b = e >> 6, ij = e & 63, i = ij >> 3, j = ij & 7;
    const int t = threadIdx.x;
    // zero this block's slice of node_preds (2048 * 450 = 921600)
    for (int z = t; z < 450; z += 256) node_preds[(size_t)e * 450 + z] = 0.0f;
    const float dx = pos[(b * 8 + i) * 3 + 0] - pos[(b * 8 + j) * 3 + 0];
    const float dy = pos[(b * 8 + i) * 3 + 1] - pos[(b * 8 + j) * 3 + 1];
    const bool msk = (dx * dx + dy * dy < 0.25f) && (i != j);
    if (t == 0) mask_out[e] = msk ? 1.0f : 0.0f;
    if (!msk) {                              // block-uniform branch
        if (t < 7) edge_out[e * 7 + t] = 0.0f;
        return;
    }
    const int h0 = t * 2;
    const u16* arow = ag + (size_t)(b * 8 + i) * 49 * 1024 + h0;
    const u16* grow = ag + (size_t)(b * 8 + j) * 49 * 1024 + 512 + h0;
    const float b10 = b1[h0], b11 = b1[h0 + 1];
    float r0 = 0.f, r1 = 0.f;
#pragma unroll 7
    for (int s = 0; s < 49; s++) {
        u32 av = *(const u32*)(arow + (size_t)s * 1024);
        u32 gv = *(const u32*)(grow + (size_t)s * 1024);
        float a0 = bfbits2f(av << 16), a1 = bfbits2f(av & 0xFFFF0000u);
        float g0 = bfbits2f(gv << 16), g1 = bfbits2f(gv & 0xFFFF0000u);
        r0 += fmaxf(a0 + g0 + b10, 0.f);
        r1 += fmaxf(a1 + g1 + b11, 0.f);
    }
    float c[7];
#pragma unroll
    for (int k = 0; k < 7; k++)
        c[k] = r0 * W2h[h0 * 7 + k] + r1 * W2h[(h0 + 1) * 7 + k];
#pragma unroll
    for (int k = 0; k < 7; k++)
#pragma unroll
        for (int off = 32; off; off >>= 1)
            c[k] += __shfl_down(c[k], off, 64);
    const int lane = t & 63, wv = t >> 6;
    if (lane == 0)
        for (int k = 0; k < 7; k++) red[wv][k] = c[k];
    __syncthreads();
    if (t == 0)
        for (int k = 0; k < 7; k++) {
            float v = red[0][k] + red[1][k] + red[2][k] + red[3][k];
            edge_out[e * 7 + k] = v * (1.f / 49.f) + bias7[k];
        }
}

// ---------- launch ----------
extern "C" void kernel_launch(void* const* d_in, const int* in_sizes, int n_in,
                              void* d_out, int out_size, void* d_ws, size_t ws_size,
                              hipStream_t stream) {
    const float* img    = (const float*)d_in[0];
    const float* pos    = (const float*)d_in[1];
    const float* W_patch= (const float*)d_in[3];
    const float* b_patch= (const float*)d_in[4];
    const float* W1a    = (const float*)d_in[5];
    const float* W1b    = (const float*)d_in[6];
    const float* b1     = (const float*)d_in[7];
    const float* W2     = (const float*)d_in[8];
    const float* b2     = (const float*)d_in[9];
    const float* Wp     = (const float*)d_in[10];
    const float* bp     = (const float*)d_in[11];
    const float* Wpv    = (const float*)d_in[12];
    const float* bpv    = (const float*)d_in[13];
    const float* Wr     = (const float*)d_in[14];
    const float* br     = (const float*)d_in[15];
    const float* Wrv    = (const float*)d_in[16];
    const float* brv    = (const float*)d_in[17];

    char* ws = (char*)d_ws;
    u16*   patches = (u16*)(ws + 0);                      // 12544*3072*2 = 77,070,336
    u16*   ag      = (u16*)(ws + 77070336);               // 12544*1024*2 = 25,690,112
    u16*   feats   = (u16*)(ws + 102760448);              // 12544*384*2  =  9,633,792
    u16*   wpb     = (u16*)(ws + 112394240);              // 384*3072*2   =  2,359,296
    u16*   w1cat   = (u16*)(ws + 114753536);              // 1024*384*2   =    786,432
    float* W2h     = (float*)(ws + 115539968);            // 512*7*4      =     14,336
    float* bias7   = (float*)(ws + 115554304);            // 7*4

    float* edge_out   = (float*)d_out;                    // 2048*7
    float* mask_out   = edge_out + 14336;                 // 2048
    float* node_preds = mask_out + 2048;                  // 32*8*3600 = 921,600

    prep_kernel<<<4096, 256, 0, stream>>>(img, patches, W_patch, wpb,
                                          W1a, W1b, w1cat,
                                          W2, b2, Wp, bp, Wpv, bpv, Wr, br, Wrv, brv,
                                          W2h, bias7);

    dim3 g1(98, 6);   // BM=128, BN=64 -> 588 blocks (~2.3/CU for barrier-drain overlap)
    gemm_bt<128, 64><<<g1, 256, 0, stream>>>(patches, wpb, feats, b_patch, 12544, 384, 3072);
    dim3 g2(196, 8);  // BM=64, BN=128 -> 1568 blocks (~6/CU, short-K GEMM)
    gemm_bt<64, 128><<<g2, 256, 0, stream>>>(feats, w1cat, ag, nullptr, 12544, 1024, 384);

    edge_kernel<<<2048, 256, 0, stream>>>(ag, pos, b1, W2h, bias7,
                                          edge_out, mask_out, node_preds);
}